// Round 11
// baseline (528.727 us; speedup 1.0000x reference)
//
#include <hip/hip_runtime.h>

typedef _Float16 half2_t __attribute__((ext_vector_type(2)));
typedef unsigned int uint;

#define D 128
#define O 64
#define UNR 8

static inline size_t align_up(size_t x, size_t a) { return (x + a - 1) & ~(a - 1); }

__device__ __forceinline__ uint pack_f16(float a, float b) {
  half2_t h;
  h.x = (_Float16)a;
  h.y = (_Float16)b;
  return *(uint*)&h;
}

__device__ __forceinline__ float dot2f(uint a, uint b, float c) {
#if defined(__has_builtin) && __has_builtin(__builtin_amdgcn_fdot2)
  return __builtin_amdgcn_fdot2(*(half2_t*)&a, *(half2_t*)&b, c, false);
#else
  half2_t ha = *(half2_t*)&a, hb = *(half2_t*)&b;
  return c + (float)ha.x * (float)hb.x + (float)ha.y * (float)hb.y;
#endif
}

__device__ __forceinline__ void fma_pair(float w, uint p, float& a0, float& a1) {
  half2_t h = *(half2_t*)&p;
  a0 += w * (float)h.x;
  a1 += w * (float)h.y;
}

// ---------------- setup kernels ----------------
// deg = in-edge count (no self loop; memset to 0 before). dinv = rsqrt(deg+1).

__global__ void count_deg_k(const int* __restrict__ col, int* __restrict__ deg, int E, int n) {
  int i = blockIdx.x * blockDim.x + threadIdx.x;
  if (i >= E) return;
  int c = col[i];
  if ((unsigned)c >= (unsigned)n) return;
  atomicAdd(&deg[c], 1);
}

__global__ void scan1_k(const int* __restrict__ deg, int* __restrict__ row_ptr,
                        int* __restrict__ bsum, float* __restrict__ dinv, int n) {
  __shared__ int s[256];
  int tid = threadIdx.x;
  int gid = blockIdx.x * 256 + tid;
  int dg = (gid < n) ? deg[gid] : 0;
  if (gid < n) dinv[gid] = rsqrtf((float)(dg + 1));
  s[tid] = dg;
  __syncthreads();
  for (int off = 1; off < 256; off <<= 1) {
    int t = (tid >= off) ? s[tid - off] : 0;
    __syncthreads();
    s[tid] += t;
    __syncthreads();
  }
  if (gid < n) row_ptr[gid] = s[tid] - dg;  // block-local exclusive
  if (tid == 255) bsum[blockIdx.x] = s[255];
}

__global__ void scan2_k(int* __restrict__ bsum, int nb) {
  __shared__ int s[512];
  int tid = threadIdx.x;
  int v = (tid < nb) ? bsum[tid] : 0;
  s[tid] = v;
  __syncthreads();
  for (int off = 1; off < 512; off <<= 1) {
    int t = (tid >= off) ? s[tid - off] : 0;
    __syncthreads();
    s[tid] += t;
    __syncthreads();
  }
  if (tid < nb) bsum[tid] = s[tid] - v;
}

__global__ void scan3_k(const int* __restrict__ bsum, const int* __restrict__ deg,
                        int* __restrict__ row_ptr, int* __restrict__ cursor, int n) {
  int gid = blockIdx.x * 256 + threadIdx.x;
  if (gid < n) {
    int r = row_ptr[gid] + bsum[blockIdx.x];
    row_ptr[gid] = r;
    cursor[gid] = r;
    if (gid == n - 1) row_ptr[n] = r + deg[gid];
  }
}

__global__ void fill_k(const int* __restrict__ rows, const int* __restrict__ cols,
                       int* __restrict__ cursor, const float* __restrict__ dinv,
                       int2* __restrict__ csr, int E, int n) {
  int i = blockIdx.x * blockDim.x + threadIdx.x;
  if (i >= E) return;
  int u = rows[i], v = cols[i];
  if ((unsigned)v >= (unsigned)n) return;  // must match count_deg_k skip
  if ((unsigned)u >= (unsigned)n) u = 0;
  int slot = atomicAdd(&cursor[v], 1);
  float nrm = dinv[u] * dinv[v];
  csr[slot] = make_int2(u, __float_as_int(nrm));
}

// softmax over hop weights + pack W to f16x2, TRANSPOSED: Wpk[dd*64+o]
__global__ void prep_k(const float* __restrict__ t, float* __restrict__ tn,
                       const float* __restrict__ W, uint* __restrict__ Wpk, int step) {
  int tid = threadIdx.x;
  if (tid < D) {
    float vals[16];
    float m = -1e30f;
    for (int k = 0; k < step; ++k) { vals[k] = t[k * D + tid]; m = fmaxf(m, vals[k]); }
    float ssum = 0.f;
    for (int k = 0; k < step; ++k) { vals[k] = expf(vals[k] - m); ssum += vals[k]; }
    float inv = 1.f / ssum;
    for (int k = 0; k < step; ++k) tn[k * D + tid] = vals[k] * inv;
  }
  for (int i = tid; i < O * 64; i += 256) {
    int o = i & 63, dd = i >> 6;  // i = dd*64 + o
    Wpk[i] = pack_f16(W[o * D + 2 * dd], W[o * D + 2 * dd + 1]);
  }
}

__global__ void init_h_k(const float* __restrict__ x, uint* __restrict__ h0, int total) {
  int i = blockIdx.x * blockDim.x + threadIdx.x;
  if (i >= total) return;
  float2 v = ((const float2*)x)[i];
  h0[i] = pack_f16(v.x, v.y);
}

// ---------------- hop: pure SpMM h_dst = A_norm * h_src ----------------
// One wave per node. WIDE gathers: one dwordx4 wave-instruction fetches
// FOUR edges' 256B rows (lane: sub=l>>4 picks the edge, q=l&15 picks the
// 16B chunk => 1KB per instruction). Partial sums combined via shfl_xor
// butterflies (16, 32). Tests the per-CU outstanding-request-cap model.

__global__ __launch_bounds__(256) void hop_k(
    const uint* __restrict__ hsrc, uint* __restrict__ hdst,
    const int* __restrict__ row_ptr, const int2* __restrict__ csr,
    const float* __restrict__ dinv, int n) {
  int wid = (blockIdx.x * blockDim.x + threadIdx.x) >> 6;
  int lane = threadIdx.x & 63;
  if (wid >= n) return;
  int v = __builtin_amdgcn_readfirstlane(wid);
  int sub = lane >> 4;  // 0..3: which edge of the quad
  int q = lane & 15;    // 0..15: 16B chunk of the 256B row

  float dv = dinv[v];
  float ns = dv * dv;  // self-loop norm
  uint4 sv = ((const uint4*)(hsrc + (size_t)v * 64))[q];  // self row chunk (early issue)

  int beg = __builtin_amdgcn_readfirstlane(row_ptr[v]);
  int end = __builtin_amdgcn_readfirstlane(row_ptr[v + 1]);

  float acc[8];
#pragma unroll
  for (int d = 0; d < 8; ++d) acc[d] = 0.f;

  for (int i = beg; i < end; i += 8) {
    int icA = i + sub, icB = i + 4 + sub;
    int iclA = icA < end - 1 ? icA : end - 1;
    int iclB = icB < end - 1 ? icB : end - 1;
    int2 eA = csr[iclA];
    int2 eB = csr[iclB];
    float wA = (icA < end) ? __int_as_float(eA.y) : 0.f;
    float wB = (icB < end) ? __int_as_float(eB.y) : 0.f;
    uint4 gA = ((const uint4*)(hsrc + (size_t)eA.x * 64))[q];  // 1KB/instr, 4 edges
    uint4 gB = ((const uint4*)(hsrc + (size_t)eB.x * 64))[q];
    fma_pair(wA, gA.x, acc[0], acc[1]);
    fma_pair(wA, gA.y, acc[2], acc[3]);
    fma_pair(wA, gA.z, acc[4], acc[5]);
    fma_pair(wA, gA.w, acc[6], acc[7]);
    fma_pair(wB, gB.x, acc[0], acc[1]);
    fma_pair(wB, gB.y, acc[2], acc[3]);
    fma_pair(wB, gB.z, acc[4], acc[5]);
    fma_pair(wB, gB.w, acc[6], acc[7]);
  }

  // combine the 4 sub-quad partial sums (lanes with equal q share dims)
#pragma unroll
  for (int d = 0; d < 8; ++d) {
    acc[d] += __shfl_xor(acc[d], 16, 64);
    acc[d] += __shfl_xor(acc[d], 32, 64);
  }
  // self-loop contribution (per-lane, dims 8q..8q+7)
  fma_pair(ns, sv.x, acc[0], acc[1]);
  fma_pair(ns, sv.y, acc[2], acc[3]);
  fma_pair(ns, sv.z, acc[4], acc[5]);
  fma_pair(ns, sv.w, acc[6], acc[7]);

  if (lane < 16) {  // 16 lanes x 16B = 256B row store
    uint4 o;
    o.x = pack_f16(acc[0], acc[1]);
    o.y = pack_f16(acc[2], acc[3]);
    o.z = pack_f16(acc[4], acc[5]);
    o.w = pack_f16(acc[6], acc[7]);
    ((uint4*)(hdst + (size_t)v * 64))[q] = o;
  }
}

// ---------------- proj ----------------
// XF16=true : hbuf slots 0..step-1 hold f16 h_0..h_{step-1}; x unused.
// XF16=false: x is fp32; hbuf slots 0..step-2 hold h_1..h_{step-1}.

#define PNW 8

template <int STEPT, bool XF16>
__global__ __launch_bounds__(256) void proj_k(
    const float* __restrict__ x, const uint* __restrict__ hbuf, size_t hstride,
    const uint* __restrict__ Wpk, const float* __restrict__ tn,
    const float* __restrict__ b, float* __restrict__ out, int n, int step) {
  __shared__ uint sy[4][64];
  int tid = threadIdx.x;
  int lane = tid & 63, wv = tid >> 6;
  uint wreg[64];
#pragma unroll
  for (int j = 0; j < 64; ++j) wreg[j] = Wpk[j * 64 + lane];  // coalesced (transposed)
  float bias = b[lane];
  float2 tt[STEPT > 0 ? STEPT : 1];
  if (STEPT > 0) {
#pragma unroll
    for (int k = 0; k < STEPT; ++k) tt[k] = ((const float2*)(tn + (size_t)k * D))[lane];
  }
  int wid = (blockIdx.x * blockDim.x + tid) >> 6;
  int vb = wid * PNW;
  int ve = vb + PNW < n ? vb + PNW : n;
  for (int v = vb; v < ve; ++v) {
    float yx, yy;
    if (STEPT > 0) {
      if (XF16) {
        uint hp = hbuf[(size_t)v * 64 + lane];
        half2_t h = *(half2_t*)&hp;
        yx = tt[0].x * (float)h.x;
        yy = tt[0].y * (float)h.y;
#pragma unroll
        for (int k = 1; k < STEPT; ++k) {
          uint hq = hbuf[(size_t)k * hstride + (size_t)v * 64 + lane];
          half2_t hh = *(half2_t*)&hq;
          yx += tt[k].x * (float)hh.x;
          yy += tt[k].y * (float)hh.y;
        }
      } else {
        float2 xv = ((const float2*)x)[(size_t)v * 64 + lane];
        yx = tt[0].x * xv.x;
        yy = tt[0].y * xv.y;
#pragma unroll
        for (int k = 1; k < STEPT; ++k) {
          uint hq = hbuf[(size_t)(k - 1) * hstride + (size_t)v * 64 + lane];
          half2_t hh = *(half2_t*)&hq;
          yx += tt[k].x * (float)hh.x;
          yy += tt[k].y * (float)hh.y;
        }
      }
    } else {
      float2 t0 = ((const float2*)tn)[lane];
      float2 xv = ((const float2*)x)[(size_t)v * 64 + lane];
      yx = t0.x * xv.x;
      yy = t0.y * xv.y;
      for (int k = 1; k < step; ++k) {
        uint hq = hbuf[(size_t)(k - 1) * hstride + (size_t)v * 64 + lane];
        half2_t hh = *(half2_t*)&hq;
        float2 tk = ((const float2*)(tn + (size_t)k * D))[lane];
        yx += tk.x * (float)hh.x;
        yy += tk.y * (float)hh.y;
      }
    }
    sy[wv][lane] = pack_f16(yx, yy);  // wave-local broadcast buffer
    float acc = bias;
#pragma unroll
    for (int qq = 0; qq < 16; ++qq) {
      uint4 yq = *(const uint4*)&sy[wv][qq * 4];  // broadcast b128 read
      acc = dot2f(yq.x, wreg[qq * 4 + 0], acc);
      acc = dot2f(yq.y, wreg[qq * 4 + 1], acc);
      acc = dot2f(yq.z, wreg[qq * 4 + 2], acc);
      acc = dot2f(yq.w, wreg[qq * 4 + 3], acc);
    }
    out[(size_t)v * O + lane] = acc;
  }
}

// ---------------- fallback path (tiny ws): R4-proven structure ----------

template <int DO_Y>
__global__ __launch_bounds__(256) void hop_f_k(
    const uint* __restrict__ h_old, uint* __restrict__ h_new, uint* __restrict__ y,
    const int* __restrict__ row_ptr, const int2* __restrict__ csr,
    const float* __restrict__ dinv, const float* __restrict__ tprev,
    const float* __restrict__ tcur, int n) {
  int wid = (blockIdx.x * blockDim.x + threadIdx.x) >> 6;
  int lane = threadIdx.x & 63;
  if (wid >= n) return;
  int v = __builtin_amdgcn_readfirstlane(wid);
  float dv = dinv[v];
  float ns = dv * dv;
  uint hp = h_old[(size_t)v * 64 + lane];
  half2_t hv = *(half2_t*)&hp;
  float hx = (float)hv.x, hy = (float)hv.y;
  float ax = ns * hx, ay = ns * hy;
  int beg = __builtin_amdgcn_readfirstlane(row_ptr[v]);
  int end = __builtin_amdgcn_readfirstlane(row_ptr[v + 1]);
  for (int i = beg; i < end; i += UNR) {
    int u[UNR];
    float w[UNR];
#pragma unroll
    for (int j = 0; j < UNR; ++j) {
      int ic = i + j;
      int icl = (ic < end - 1) ? ic : (end - 1);
      int2 e = csr[icl];
      u[j] = e.x;
      w[j] = (ic < end) ? __int_as_float(e.y) : 0.f;
    }
    uint g[UNR];
#pragma unroll
    for (int j = 0; j < UNR; ++j) g[j] = h_old[(size_t)u[j] * 64 + lane];
#pragma unroll
    for (int j = 0; j < UNR; ++j) {
      half2_t h = *(half2_t*)&g[j];
      ax += w[j] * (float)h.x;
      ay += w[j] * (float)h.y;
    }
  }
  h_new[(size_t)v * 64 + lane] = pack_f16(ax, ay);
  if (DO_Y) {
    float2 ta = ((const float2*)tprev)[lane];
    float2 tb = ((const float2*)tcur)[lane];
    float yx = ta.x * hx + tb.x * ax;
    float yy = ta.y * hy + tb.y * ay;
    if (DO_Y == 2) {
      uint yo = y[(size_t)v * 64 + lane];
      half2_t yh = *(half2_t*)&yo;
      yx += (float)yh.x;
      yy += (float)yh.y;
    }
    y[(size_t)v * 64 + lane] = pack_f16(yx, yy);
  }
}

__global__ __launch_bounds__(256) void proj_y_k(
    const uint* __restrict__ y, const uint* __restrict__ Wpk,
    const float* __restrict__ b, float* __restrict__ out, int n, int nwaves) {
  int lane = threadIdx.x & 63;
  int wid = (blockIdx.x * blockDim.x + threadIdx.x) >> 6;
  uint wreg[64];
#pragma unroll
  for (int j = 0; j < 64; ++j) wreg[j] = Wpk[j * 64 + lane];  // transposed layout
  float bias = b[lane];
  for (int v = wid; v < n; v += nwaves) {
    int vu = __builtin_amdgcn_readfirstlane(v);
    const uint* yrow = y + (size_t)vu * 64;
    float acc = bias;
#pragma unroll
    for (int dd = 0; dd < 64; ++dd) acc = dot2f(yrow[dd], wreg[dd], acc);
    out[(size_t)vu * O + lane] = acc;
  }
}

// ---------------- launch ----------------

extern "C" void kernel_launch(void* const* d_in, const int* in_sizes, int n_in,
                              void* d_out, int out_size, void* d_ws, size_t ws_size,
                              hipStream_t stream) {
  const float* x = (const float*)d_in[0];
  const int* ei = (const int*)d_in[1];
  const float* t = (const float*)d_in[2];
  const float* W = (const float*)d_in[3];
  const float* b = (const float*)d_in[4];
  float* out = (float*)d_out;

  int n = in_sizes[0] / D;
  int E = in_sizes[1] / 2;
  int step = in_sizes[2] / D;  // = 10
  const int* rows = ei;        // sources
  const int* cols = ei + E;    // targets

  char* p = (char*)d_ws;
  auto alloc = [&](size_t bytes) { char* r = p; p += align_up(bytes, 256); return r; };
  int*   deg     = (int*)alloc((size_t)n * 4);
  float* dinv    = (float*)alloc((size_t)n * 4);
  int*   row_ptr = (int*)alloc((size_t)(n + 1) * 4);
  int*   cursor  = (int*)alloc((size_t)n * 4);
  int*   bsum    = (int*)alloc(2048);
  int2*  csr     = (int2*)alloc((size_t)E * 8);
  float* tn      = (float*)alloc((size_t)step * D * 4);
  uint*  Wpk     = (uint*)alloc((size_t)O * 64 * 4);

  size_t NS = (size_t)n * 64;  // uints per h buffer
  size_t base = (size_t)(p - (char*)d_ws);
  bool fullx = (ws_size >= base + (size_t)step * NS * 4) && (step >= 3);       // 10 slots
  bool full  = (ws_size >= base + (size_t)(step - 1) * NS * 4) && (step >= 3); // 9 slots

  // ---- common setup ----
  hipMemsetAsync(deg, 0, (size_t)n * 4, stream);
  int nb1 = (n + 255) / 256;
  count_deg_k<<<(E + 255) / 256, 256, 0, stream>>>(cols, deg, E, n);
  scan1_k<<<nb1, 256, 0, stream>>>(deg, row_ptr, bsum, dinv, n);
  scan2_k<<<1, 512, 0, stream>>>(bsum, nb1);
  scan3_k<<<nb1, 256, 0, stream>>>(bsum, deg, row_ptr, cursor, n);
  fill_k<<<(E + 255) / 256, 256, 0, stream>>>(rows, cols, cursor, dinv, csr, E, n);
  prep_k<<<1, 256, 0, stream>>>(t, tn, W, Wpk, step);

  int hop_blocks = (n + 3) / 4;  // 1 node/wave, 4 waves/block
  int proj_blocks = (n + PNW * 4 - 1) / (PNW * 4);

  if (fullx) {
    // 10 slots: slot k = h_k (slot 0 = f16(x)); proj reads f16 only
    uint* hbuf = (uint*)alloc((size_t)step * NS * 4);
    init_h_k<<<((size_t)NS + 255) / 256, 256, 0, stream>>>(x, hbuf, (int)NS);
    for (int k = 1; k < step; ++k) {
      hop_k<<<hop_blocks, 256, 0, stream>>>(hbuf + (size_t)(k - 1) * NS,
                                            hbuf + (size_t)k * NS, row_ptr, csr, dinv, n);
    }
    if (step == 10)
      proj_k<10, true><<<proj_blocks, 256, 0, stream>>>(x, hbuf, NS, Wpk, tn, b, out, n, step);
    else
      proj_k<0, false><<<proj_blocks, 256, 0, stream>>>(x, hbuf + NS, NS, Wpk, tn, b, out, n, step);
  } else if (full) {
    // 9 slots: h0 parked in slot step-2, overwritten by the final hop
    uint* hbuf = (uint*)alloc((size_t)(step - 1) * NS * 4);
    uint* h0 = hbuf + (size_t)(step - 2) * NS;
    init_h_k<<<((size_t)NS + 255) / 256, 256, 0, stream>>>(x, h0, (int)NS);
    hop_k<<<hop_blocks, 256, 0, stream>>>(h0, hbuf, row_ptr, csr, dinv, n);
    for (int k = 2; k < step; ++k) {
      hop_k<<<hop_blocks, 256, 0, stream>>>(hbuf + (size_t)(k - 2) * NS,
                                            hbuf + (size_t)(k - 1) * NS, row_ptr, csr, dinv, n);
    }
    if (step == 10)
      proj_k<10, false><<<proj_blocks, 256, 0, stream>>>(x, hbuf, NS, Wpk, tn, b, out, n, step);
    else
      proj_k<0, false><<<proj_blocks, 256, 0, stream>>>(x, hbuf, NS, Wpk, tn, b, out, n, step);
  } else {
    // fallback: ping-pong with fused y (3 buffers)
    uint* h_a  = (uint*)alloc(NS * 4);
    uint* h_b  = (uint*)alloc(NS * 4);
    uint* ybuf = (uint*)alloc(NS * 4);
    init_h_k<<<((size_t)NS + 255) / 256, 256, 0, stream>>>(x, h_a, (int)NS);
    uint* ho = h_a;
    uint* hn = h_b;
    for (int k = 1; k < step; ++k) {
      const float* tp = tn + (size_t)(k - 1) * D;
      const float* tc = tn + (size_t)k * D;
      if (k & 1) {
        if (k == 1)
          hop_f_k<1><<<hop_blocks, 256, 0, stream>>>(ho, hn, ybuf, row_ptr, csr, dinv, tp, tc, n);
        else
          hop_f_k<2><<<hop_blocks, 256, 0, stream>>>(ho, hn, ybuf, row_ptr, csr, dinv, tp, tc, n);
      } else {
        hop_f_k<0><<<hop_blocks, 256, 0, stream>>>(ho, hn, ybuf, row_ptr, csr, dinv, tp, tc, n);
      }
      uint* tmp = ho; ho = hn; hn = tmp;
    }
    proj_y_k<<<512, 256, 0, stream>>>(ybuf, Wpk, b, out, n, 2048);
  }
}